// Round 4
// baseline (119.785 us; speedup 1.0000x reference)
//
#include <hip/hip_runtime.h>
#include <math.h>

#define KD 768
#define T_SEL 8

typedef float f32x4v __attribute__((ext_vector_type(4)));
typedef __bf16 bf16x8 __attribute__((ext_vector_type(8)));

__device__ __forceinline__ float wave_sum(float x) {
#pragma unroll
  for (int o = 32; o > 0; o >>= 1) x += __shfl_xor(x, o, 64);
  return x;
}

__device__ __forceinline__ unsigned short f2bf(float x) {
  unsigned int u = __float_as_uint(x);
  unsigned int r = (u + 0x7fffu + ((u >> 16) & 1u)) >> 16;
  return (unsigned short)r;
}

__device__ __forceinline__ ushort4 cvt4(float4 a) {
  ushort4 us;
  us.x = f2bf(a.x); us.y = f2bf(a.y); us.z = f2bf(a.z); us.w = f2bf(a.w);
  return us;
}

__device__ __forceinline__ void async_copy16(void* lds, const void* g) {
  __builtin_amdgcn_global_load_lds(
      (const __attribute__((address_space(1))) unsigned int*)g,
      (__attribute__((address_space(3))) unsigned int*)lds, 16, 0, 0);
}

// ---------------- kernel 1: streaming prep (norms + bf16 convert + top-8 select + pad) ----
// rows: [0,4096) vhat/v/g  [4096,5120) negatives  [5120,5184) F  [5184,5248) zero-pad A
__global__ __launch_bounds__(256) void k_prep(
    const float* __restrict__ v, const float* __restrict__ vhat,
    const float* __restrict__ negs, const float* __restrict__ F,
    const float* __restrict__ g,
    unsigned short* __restrict__ A_bf, unsigned short* __restrict__ B_bf,
    float* __restrict__ nv2, float* __restrict__ true_d,
    float* __restrict__ colBn, unsigned long long* __restrict__ selmask,
    float* __restrict__ gsum) {
  const int w = threadIdx.x >> 6, l = threadIdx.x & 63;
  const int row = blockIdx.x * 4 + w;
  if (row < 4096) {
    const float4* vr = (const float4*)(vhat + (size_t)row * KD);
    const float4* vv = (const float4*)(v + (size_t)row * KD);
    ushort4* outb = (ushort4*)(A_bf + (size_t)row * KD);
    float s2 = 0.f, td2 = 0.f;
#pragma unroll
    for (int i = 0; i < 3; ++i) {
      float4 a = vr[i * 64 + l];
      float4 b = vv[i * 64 + l];
      s2 += a.x * a.x + a.y * a.y + a.z * a.z + a.w * a.w;
      float dx = a.x - b.x, dy = a.y - b.y, dz = a.z - b.z, dw = a.w - b.w;
      td2 += dx * dx + dy * dy + dz * dz + dw * dw;
      outb[i * 64 + l] = cvt4(a);
    }
    s2 = wave_sum(s2);
    td2 = wave_sum(td2);
    // top-8-smallest selection on g row (rank counting, top_k tie semantics)
    const float gl = g[(size_t)row * 64 + l];
    int rank = 0;
#pragma unroll
    for (int d = 1; d < 64; ++d) {
      const float o = __shfl_xor(gl, d, 64);
      const int j = l ^ d;
      rank += (o < gl || (o == gl && j < l)) ? 1 : 0;
    }
    const bool sel = rank < T_SEL;
    const float gs = wave_sum(sel ? gl : 0.f) + 1e-10f;
    const unsigned long long sm = __ballot(sel);
    if (l == 0) {
      nv2[row] = s2;
      true_d[row] = sqrtf(fmaxf(td2, 0.f) + 1e-8f);
      selmask[row] = sm;
      gsum[row] = gs;
    }
  } else if (row < 5120) {
    const int r = row - 4096;
    const float4* nr = (const float4*)(negs + (size_t)r * KD);
    ushort4* outb = (ushort4*)(B_bf + (size_t)r * KD);
    float s2 = 0.f;
#pragma unroll
    for (int i = 0; i < 3; ++i) {
      float4 a = nr[i * 64 + l];
      s2 += a.x * a.x + a.y * a.y + a.z * a.z + a.w * a.w;
      outb[i * 64 + l] = cvt4(a);
    }
    s2 = wave_sum(s2);
    if (l == 0) colBn[r] = s2;
  } else if (row < 5184) {
    const int r = row - 5120;
    const float4* fr4 = (const float4*)(F + (size_t)r * KD);
    ushort4* ob1 = (ushort4*)(B_bf + (size_t)(1024 + r) * KD);
    ushort4* ob2 = (ushort4*)(A_bf + (size_t)(4096 + r) * KD);
    float s2 = 0.f;
#pragma unroll
    for (int i = 0; i < 3; ++i) {
      float4 a = fr4[i * 64 + l];
      s2 += a.x * a.x + a.y * a.y + a.z * a.z + a.w * a.w;
      ushort4 us = cvt4(a);
      ob1[i * 64 + l] = us;
      ob2[i * 64 + l] = us;
    }
    s2 = wave_sum(s2);
    if (l == 0) colBn[1024 + r] = s2;
  } else {
    const int r = row - 5184;
    ushort4* outb = (ushort4*)(A_bf + (size_t)(4160 + r) * KD);
    ushort4 z; z.x = 0; z.y = 0; z.z = 0; z.w = 0;
#pragma unroll
    for (int i = 0; i < 3; ++i) outb[i * 64 + l] = z;
  }
}

// ---------------- kernel 2: bf16 MFMA GEMM, fused Ju / Jt / ortho epilogues ----------------
// grid 545: bid<544 -> tm=bid&31, tn=bid>>5 (17 col tiles); bid==544 -> ortho tile (tm=32,tn=16).
// 256 threads, 4 waves (2x2), wave tile 64x32, BK=64.
__global__ __launch_bounds__(256) void k_gemm(
    const unsigned short* __restrict__ Abf, const unsigned short* __restrict__ Bbf,
    const float* __restrict__ nv2, const float* __restrict__ colBn,
    const float* __restrict__ true_d, const int* __restrict__ mask,
    const float* __restrict__ g, const unsigned long long* __restrict__ selmask,
    const float* __restrict__ gsum,
    float* __restrict__ gemm_part, float* __restrict__ or_sum) {
  __shared__ char smem[24576];  // A: 128 rows x 128B = 16 KB, B: 64 rows x 128B = 8 KB
  char* sA = smem;
  char* sB = smem + 16384;

  const int tid = threadIdx.x;
  const int w = tid >> 6;
  const int l = tid & 63;
  const int bid = blockIdx.x;
  const int tm = (bid == 544) ? 32 : (bid & 31);
  const int tn = (bid == 544) ? 16 : (bid >> 5);

  const int row0 = tm * 128;
  const int col0 = tn * 64;
  const int wr = w >> 1, wc = w & 1;
  const int lr = l >> 3;  // row within an 8-row 1KB chunk
  const int sl = l & 7;   // 16B slot within a 128B row

  f32x4v accf[4][2] = {};

  for (int kt = 0; kt < 12; ++kt) {
    const int k0 = kt * 64;
    if (kt) __syncthreads();
    // stage 24 chunks of 1KB (A: 0..15, B: 16..23); wave w does {w, w+4, ..., w+20}
#pragma unroll
    for (int i = 0; i < 6; ++i) {
      const int c = w + i * 4;
      if (c < 16) {
        const int rr = c * 8 + lr;
        const int ss = sl ^ (rr & 7);  // inverse source swizzle (linear LDS dest)
        async_copy16(sA + c * 1024, Abf + ((size_t)(row0 + rr) * KD + k0 + ss * 8));
      } else {
        const int cc = c - 16;
        const int rr = cc * 8 + lr;
        const int ss = sl ^ (rr & 7);
        async_copy16(sB + cc * 1024, Bbf + ((size_t)(col0 + rr) * KD + k0 + ss * 8));
      }
    }
    __syncthreads();

    const int fr = l & 15, fq = l >> 4;
#pragma unroll
    for (int kk = 0; kk < 2; ++kk) {
      bf16x8 af[4], bfr[2];
#pragma unroll
      for (int m = 0; m < 4; ++m) {
        const int rr = wr * 64 + m * 16 + fr;
        const int slot = (fq + kk * 4) ^ (rr & 7);
        af[m] = *(const bf16x8*)(sA + rr * 128 + slot * 16);
      }
#pragma unroll
      for (int n = 0; n < 2; ++n) {
        const int rr = wc * 32 + n * 16 + fr;
        const int slot = (fq + kk * 4) ^ (rr & 7);
        bfr[n] = *(const bf16x8*)(sB + rr * 128 + slot * 16);
      }
#pragma unroll
      for (int m = 0; m < 4; ++m)
#pragma unroll
        for (int n = 0; n < 2; ++n)
          accf[m][n] = __builtin_amdgcn_mfma_f32_16x16x32_bf16(af[m], bfr[n], accf[m][n], 0, 0, 0);
    }
  }

  const int fr = l & 15, fq = l >> 4;
  float local = 0.f;
  if (tn < 16) {
    // Ju hinge region: h = mask * max(1 + true_d - sqrt(max(d2,0)+eps), 0), scaled /1024
#pragma unroll
    for (int m = 0; m < 4; ++m) {
#pragma unroll
      for (int j = 0; j < 4; ++j) {
        const int grow = row0 + wr * 64 + m * 16 + fq * 4 + j;
        const float nv = nv2[grow];
        const float td = true_d[grow];
        const float mf = (float)mask[grow];
#pragma unroll
        for (int n = 0; n < 2; ++n) {
          const int gcol = col0 + wc * 32 + n * 16 + fr;
          const float s = accf[m][n][j];
          const float d2 = nv + colBn[gcol] - 2.f * s;
          const float dn = sqrtf(fmaxf(d2, 0.f) + 1e-8f);
          local += mf * fmaxf(1.f + td - dn, 0.f);
        }
      }
    }
    local *= (1.f / 1024.f);
  } else if (tm < 32) {
    // Jt region: cols are F-columns; flat sum of selected hinge terms, scaled /8
#pragma unroll
    for (int m = 0; m < 4; ++m) {
#pragma unroll
      for (int j = 0; j < 4; ++j) {
        const int grow = row0 + wr * 64 + m * 16 + fq * 4 + j;
        const float nv = nv2[grow];
        const float td = true_d[grow];
        const float mf = (float)mask[grow];
        const float gs = gsum[grow];
        const unsigned long long msk = selmask[grow];
#pragma unroll
        for (int n = 0; n < 2; ++n) {
          const int k = wc * 32 + n * 16 + fr;  // F index 0..63
          if ((msk >> k) & 1ull) {
            const float s = accf[m][n][j];
            const float d2 = nv + colBn[1024 + k] - 2.f * s;
            const float dn = sqrtf(fmaxf(d2, 0.f) + 1e-8f);
            const float gt = g[(size_t)grow * 64 + k] / gs;
            const float mt = (1.f - gt) * (1.f - gt);
            local += mf * fmaxf(mt + td - dn, 0.f);
          }
        }
      }
    }
    local *= (1.f / (float)T_SEL);
  } else {
    // ortho: F F^T - I, rows 4096..4159 only (4160+ are zero-pad)
#pragma unroll
    for (int m = 0; m < 4; ++m) {
#pragma unroll
      for (int j = 0; j < 4; ++j) {
        const int grow = row0 + wr * 64 + m * 16 + fq * 4 + j;
        if (grow < 4160) {
          const int i2 = grow - 4096;
#pragma unroll
          for (int n = 0; n < 2; ++n) {
            const int j2 = wc * 32 + n * 16 + fr;
            const float d = accf[m][n][j] - ((i2 == j2) ? 1.f : 0.f);
            local += d * d;
          }
        }
      }
    }
  }

  local = wave_sum(local);
  __syncthreads();
  float* red = (float*)smem;
  if (l == 0) red[w] = local;
  __syncthreads();
  if (tid == 0) {
    const float t = red[0] + red[1] + red[2] + red[3];
    if (bid == 544) or_sum[0] = t;
    else gemm_part[bid] = t;
  }
}

// ---------------- kernel 3: final combine ----------------
__global__ __launch_bounds__(256) void k_final(
    const float* __restrict__ gemm_part, const float* __restrict__ or_sum,
    const int* __restrict__ mask, float* __restrict__ out) {
  const int tid = threadIdx.x;
  float sp = 0.f, sm = 0.f;
  for (int i = tid; i < 544; i += 256) sp += gemm_part[i];
  for (int i = tid; i < 4096; i += 256) sm += (float)mask[i];
  sp = wave_sum(sp);
  sm = wave_sum(sm);
  __shared__ float r[2][4];
  const int w = tid >> 6, l = tid & 63;
  if (l == 0) { r[0][w] = sp; r[1][w] = sm; }
  __syncthreads();
  if (tid == 0) {
    const float parts = r[0][0] + r[0][1] + r[0][2] + r[0][3];
    const float msum = fmaxf(r[1][0] + r[1][1] + r[1][2] + r[1][3], 1.f);
    out[0] = parts / msum + 0.01f * or_sum[0];
  }
}

extern "C" void kernel_launch(void* const* d_in, const int* in_sizes, int n_in,
                              void* d_out, int out_size, void* d_ws, size_t ws_size,
                              hipStream_t stream) {
  const float* v = (const float*)d_in[0];
  const float* vhat = (const float*)d_in[1];
  const float* g = (const float*)d_in[2];
  const float* F = (const float*)d_in[3];
  const float* negs = (const float*)d_in[4];
  const int* mask = (const int*)d_in[5];
  float* out = (float*)d_out;

  char* ws = (char*)d_ws;
  float* true_d = (float*)(ws + 0);                       // 4096 f32 = 16 KB
  float* nv2 = (float*)(ws + 16384);                      // 4096 f32 = 16 KB
  float* colBn = (float*)(ws + 32768);                    // 1088 f32 (pad to 8 KB)
  float* gsum = (float*)(ws + 40960);                     // 4096 f32 = 16 KB
  unsigned long long* selmask = (unsigned long long*)(ws + 57344);  // 4096 u64 = 32 KB
  float* gemm_part = (float*)(ws + 90112);                // 544 f32 (pad to 4 KB)
  float* or_sum = (float*)(ws + 94208);                   // 1 f32
  unsigned short* A_bf = (unsigned short*)(ws + 98304);   // 4224x768 bf16 = 6.49 MB
  unsigned short* B_bf = (unsigned short*)(ws + 6586368); // 1088x768 bf16 = 1.67 MB

  hipLaunchKernelGGL(k_prep, dim3(1312), dim3(256), 0, stream, v, vhat, negs, F, g,
                     A_bf, B_bf, nv2, true_d, colBn, selmask, gsum);
  hipLaunchKernelGGL(k_gemm, dim3(545), dim3(256), 0, stream, A_bf, B_bf,
                     nv2, colBn, true_d, mask, g, selmask, gsum, gemm_part, or_sum);
  hipLaunchKernelGGL(k_final, dim3(1), dim3(256), 0, stream, gemm_part, or_sum, mask, out);
}

// Round 5
// 102.523 us; speedup vs baseline: 1.1684x; 1.1684x over previous
//
#include <hip/hip_runtime.h>
#include <math.h>

#define KD 768
#define T_SEL 8

typedef float f32x4v __attribute__((ext_vector_type(4)));
typedef __bf16 bf16x8 __attribute__((ext_vector_type(8)));

__device__ __forceinline__ float wave_sum(float x) {
#pragma unroll
  for (int o = 32; o > 0; o >>= 1) x += __shfl_xor(x, o, 64);
  return x;
}

__device__ __forceinline__ unsigned short f2bf(float x) {
  unsigned int u = __float_as_uint(x);
  unsigned int r = (u + 0x7fffu + ((u >> 16) & 1u)) >> 16;
  return (unsigned short)r;
}

__device__ __forceinline__ ushort4 cvt4(float4 a) {
  ushort4 us;
  us.x = f2bf(a.x); us.y = f2bf(a.y); us.z = f2bf(a.z); us.w = f2bf(a.w);
  return us;
}

__device__ __forceinline__ void async_copy16(void* lds, const void* g) {
  __builtin_amdgcn_global_load_lds(
      (const __attribute__((address_space(1))) unsigned int*)g,
      (__attribute__((address_space(3))) unsigned int*)lds, 16, 0, 0);
}

// ---------------- kernel 1: streaming prep (norms + bf16 convert + pad) ----------------
// rows: [0,4096) vhat/v  [4096,5120) negatives  [5120,5184) F  [5184,5248) zero-pad A
__global__ __launch_bounds__(256) void k_prep(
    const float* __restrict__ v, const float* __restrict__ vhat,
    const float* __restrict__ negs, const float* __restrict__ F,
    unsigned short* __restrict__ A_bf, unsigned short* __restrict__ B_bf,
    float* __restrict__ nv2, float* __restrict__ true_d,
    float* __restrict__ colBn) {
  const int w = threadIdx.x >> 6, l = threadIdx.x & 63;
  const int row = blockIdx.x * 4 + w;
  if (row < 4096) {
    const float4* vr = (const float4*)(vhat + (size_t)row * KD);
    const float4* vv = (const float4*)(v + (size_t)row * KD);
    ushort4* outb = (ushort4*)(A_bf + (size_t)row * KD);
    float s2 = 0.f, td2 = 0.f;
#pragma unroll
    for (int i = 0; i < 3; ++i) {
      float4 a = vr[i * 64 + l];
      float4 b = vv[i * 64 + l];
      s2 += a.x * a.x + a.y * a.y + a.z * a.z + a.w * a.w;
      float dx = a.x - b.x, dy = a.y - b.y, dz = a.z - b.z, dw = a.w - b.w;
      td2 += dx * dx + dy * dy + dz * dz + dw * dw;
      outb[i * 64 + l] = cvt4(a);
    }
    s2 = wave_sum(s2);
    td2 = wave_sum(td2);
    if (l == 0) {
      nv2[row] = s2;
      true_d[row] = sqrtf(fmaxf(td2, 0.f) + 1e-8f);
    }
  } else if (row < 5120) {
    const int r = row - 4096;
    const float4* nr = (const float4*)(negs + (size_t)r * KD);
    ushort4* outb = (ushort4*)(B_bf + (size_t)r * KD);
    float s2 = 0.f;
#pragma unroll
    for (int i = 0; i < 3; ++i) {
      float4 a = nr[i * 64 + l];
      s2 += a.x * a.x + a.y * a.y + a.z * a.z + a.w * a.w;
      outb[i * 64 + l] = cvt4(a);
    }
    s2 = wave_sum(s2);
    if (l == 0) colBn[r] = s2;
  } else if (row < 5184) {
    const int r = row - 5120;
    const float4* fr4 = (const float4*)(F + (size_t)r * KD);
    ushort4* ob1 = (ushort4*)(B_bf + (size_t)(1024 + r) * KD);
    ushort4* ob2 = (ushort4*)(A_bf + (size_t)(4096 + r) * KD);
    float s2 = 0.f;
#pragma unroll
    for (int i = 0; i < 3; ++i) {
      float4 a = fr4[i * 64 + l];
      s2 += a.x * a.x + a.y * a.y + a.z * a.z + a.w * a.w;
      ushort4 us = cvt4(a);
      ob1[i * 64 + l] = us;
      ob2[i * 64 + l] = us;
    }
    s2 = wave_sum(s2);
    if (l == 0) colBn[1024 + r] = s2;
  } else {
    const int r = row - 5184;
    ushort4* outb = (ushort4*)(A_bf + (size_t)(4160 + r) * KD);
    ushort4 z; z.x = 0; z.y = 0; z.z = 0; z.w = 0;
#pragma unroll
    for (int i = 0; i < 3; ++i) outb[i * 64 + l] = z;
  }
}

// ---------------- kernel 2: bf16 MFMA GEMM, 2-phase double-buffered ----------------
// grid 545: bid<512 -> Ju tiles (tm=bid&31, tn=bid>>5); bid in [512,544) -> S tiles
// (tm=bid-512, tn=16); bid==544 -> ortho tile (tm=32, tn=16).
// 256 threads, 4 waves (2x2), wave tile 64x32, BK=64, LDS dbuf 2x24KB.
__global__ __launch_bounds__(256) void k_gemm(
    const unsigned short* __restrict__ Abf, const unsigned short* __restrict__ Bbf,
    const float* __restrict__ nv2, const float* __restrict__ colBn,
    const float* __restrict__ true_d, const int* __restrict__ mask,
    float* __restrict__ S, float* __restrict__ gemm_part, float* __restrict__ or_sum) {
  __shared__ char smem[49152];  // per buf: A 128x128B = 16KB, B 64x128B = 8KB

  const int tid = threadIdx.x;
  const int w = tid >> 6;
  const int l = tid & 63;
  const int bid = blockIdx.x;
  int tm, tn;
  if (bid < 512) { tm = bid & 31; tn = bid >> 5; }
  else if (bid < 544) { tm = bid - 512; tn = 16; }
  else { tm = 32; tn = 16; }

  const int row0 = tm * 128;
  const int col0 = tn * 64;
  const int wr = w >> 1, wc = w & 1;
  const int lr = l >> 3;  // row within an 8-row 1KB chunk
  const int sl = l & 7;   // 16B slot within a 128B row

  f32x4v accf[4][2] = {};

  // stage K-tile kt into buffer p (24 chunks of 1KB; wave w does {w, w+4, ..., w+20})
#define STAGE(p, kt)                                                                   \
  {                                                                                    \
    char* sA_ = smem + (p)*24576;                                                      \
    char* sB_ = sA_ + 16384;                                                           \
    const int k0_ = (kt)*64;                                                           \
    _Pragma("unroll") for (int i = 0; i < 6; ++i) {                                    \
      const int c = w + i * 4;                                                         \
      if (c < 16) {                                                                    \
        const int rr = c * 8 + lr;                                                     \
        const int ss = sl ^ (rr & 7);                                                  \
        async_copy16(sA_ + c * 1024, Abf + ((size_t)(row0 + rr) * KD + k0_ + ss * 8)); \
      } else {                                                                         \
        const int cc = c - 16;                                                         \
        const int rr = cc * 8 + lr;                                                    \
        const int ss = sl ^ (rr & 7);                                                  \
        async_copy16(sB_ + cc * 1024, Bbf + ((size_t)(col0 + rr) * KD + k0_ + ss * 8));\
      }                                                                                \
    }                                                                                  \
  }

  const int fr = l & 15, fq = l >> 4;
  STAGE(0, 0);
  __syncthreads();  // drains vmcnt(0): buf0 ready
  int cur = 0;
  for (int kt = 0; kt < 12; ++kt) {
    if (kt + 1 < 12) STAGE(cur ^ 1, kt + 1);  // prefetch next tile into other buffer
    char* sA = smem + cur * 24576;
    char* sB = sA + 16384;
#pragma unroll
    for (int kk = 0; kk < 2; ++kk) {
      bf16x8 af[4], bfr[2];
#pragma unroll
      for (int m = 0; m < 4; ++m) {
        const int rr = wr * 64 + m * 16 + fr;
        const int slot = (fq + kk * 4) ^ (rr & 7);
        af[m] = *(const bf16x8*)(sA + rr * 128 + slot * 16);
      }
#pragma unroll
      for (int n = 0; n < 2; ++n) {
        const int rr = wc * 32 + n * 16 + fr;
        const int slot = (fq + kk * 4) ^ (rr & 7);
        bfr[n] = *(const bf16x8*)(sB + rr * 128 + slot * 16);
      }
#pragma unroll
      for (int m = 0; m < 4; ++m)
#pragma unroll
        for (int n = 0; n < 2; ++n)
          accf[m][n] = __builtin_amdgcn_mfma_f32_16x16x32_bf16(af[m], bfr[n], accf[m][n], 0, 0, 0);
    }
    __syncthreads();  // all waves' prefetch landed + buf[cur] fully consumed
    cur ^= 1;
  }
#undef STAGE

  float local = 0.f;
  if (tn < 16) {
    // Ju hinge: h = mask * max(1 + true_d - sqrt(max(d2,0)+eps), 0)
#pragma unroll
    for (int m = 0; m < 4; ++m) {
#pragma unroll
      for (int j = 0; j < 4; ++j) {
        const int grow = row0 + wr * 64 + m * 16 + fq * 4 + j;
        const float nv = nv2[grow];
        const float td = true_d[grow];
        const float mf = (float)mask[grow];
#pragma unroll
        for (int n = 0; n < 2; ++n) {
          const int gcol = col0 + wc * 32 + n * 16 + fr;
          const float s = accf[m][n][j];
          const float d2 = nv + colBn[gcol] - 2.f * s;
          const float dn = sqrtf(fmaxf(d2, 0.f) + 1e-8f);
          local += mf * fmaxf(1.f + td - dn, 0.f);
        }
      }
    }
  } else if (tm < 32) {
    // S store: vhat . F_k
#pragma unroll
    for (int m = 0; m < 4; ++m) {
#pragma unroll
      for (int j = 0; j < 4; ++j) {
        const int grow = row0 + wr * 64 + m * 16 + fq * 4 + j;
#pragma unroll
        for (int n = 0; n < 2; ++n) {
          const int gcol = col0 + wc * 32 + n * 16 + fr;
          S[(size_t)grow * 64 + (gcol - 1024)] = accf[m][n][j];
        }
      }
    }
  } else {
    // ortho: F F^T - I, rows 4096..4159 only (4160+ zero-pad)
#pragma unroll
    for (int m = 0; m < 4; ++m) {
#pragma unroll
      for (int j = 0; j < 4; ++j) {
        const int grow = row0 + wr * 64 + m * 16 + fq * 4 + j;
        if (grow < 4160) {
          const int i2 = grow - 4096;
#pragma unroll
          for (int n = 0; n < 2; ++n) {
            const int j2 = wc * 32 + n * 16 + fr;
            const float d = accf[m][n][j] - ((i2 == j2) ? 1.f : 0.f);
            local += d * d;
          }
        }
      }
    }
  }

  local = wave_sum(local);
  __syncthreads();
  float* red = (float*)smem;
  if (l == 0) red[w] = local;
  __syncthreads();
  if (tid == 0) {
    const float t = red[0] + red[1] + red[2] + red[3];
    if (bid == 544) or_sum[0] = t;
    else gemm_part[bid] = t;
  }
}

// ---------------- kernel 3: Jt via rank-based top-8 ----------------
__global__ __launch_bounds__(256) void k_jt(
    const float* __restrict__ g, const float* __restrict__ S,
    const float* __restrict__ nv2, const float* __restrict__ true_d,
    const float* __restrict__ colBn, const int* __restrict__ mask,
    float* __restrict__ jt_part, float* __restrict__ ms_part) {
  const int w = threadIdx.x >> 6, l = threadIdx.x & 63;
  const int row = blockIdx.x * 4 + w;
  const float gl = g[(size_t)row * 64 + l];
  int rank = 0;
#pragma unroll
  for (int d = 1; d < 64; ++d) {
    const float o = __shfl_xor(gl, d, 64);
    const int j = l ^ d;
    rank += (o < gl || (o == gl && j < l)) ? 1 : 0;
  }
  const bool sel = rank < T_SEL;
  const float gsum = wave_sum(sel ? gl : 0.f) + 1e-10f;
  const float s = S[(size_t)row * 64 + l];
  const float d2 = nv2[row] + colBn[1024 + l] - 2.f * s;
  const float dneg = sqrtf(fmaxf(d2, 0.f) + 1e-8f);
  const float gt = gl / gsum;
  const float mt = (1.f - gt) * (1.f - gt);
  const float td = true_d[row];
  const float term = sel ? fmaxf(mt + td - dneg, 0.f) : 0.f;
  const float jt = wave_sum(term);
  const float mf = (float)mask[row];

  __shared__ float red[2][4];
  if (l == 0) {
    red[0][w] = jt * mf;
    red[1][w] = mf;
  }
  __syncthreads();
  if (threadIdx.x == 0) {
    jt_part[blockIdx.x] = red[0][0] + red[0][1] + red[0][2] + red[0][3];
    ms_part[blockIdx.x] = red[1][0] + red[1][1] + red[1][2] + red[1][3];
  }
}

// ---------------- kernel 4: final combine ----------------
__global__ __launch_bounds__(256) void k_final(
    const float* __restrict__ jt_part, const float* __restrict__ ms_part,
    const float* __restrict__ gemm_part, const float* __restrict__ or_sum,
    float* __restrict__ out) {
  const int tid = threadIdx.x;
  float sj = 0.f, sm = 0.f, su = 0.f;
  for (int i = tid; i < 1024; i += 256) {
    sj += jt_part[i];
    sm += ms_part[i];
  }
  for (int i = tid; i < 544; i += 256) su += gemm_part[i];
  sj = wave_sum(sj);
  sm = wave_sum(sm);
  su = wave_sum(su);
  __shared__ float r[3][4];
  const int w = tid >> 6, l = tid & 63;
  if (l == 0) { r[0][w] = sj; r[1][w] = sm; r[2][w] = su; }
  __syncthreads();
  if (tid == 0) {
    const float jt = r[0][0] + r[0][1] + r[0][2] + r[0][3];
    float ms = r[1][0] + r[1][1] + r[1][2] + r[1][3];
    const float ju = r[2][0] + r[2][1] + r[2][2] + r[2][3];
    ms = fmaxf(ms, 1.f);
    out[0] = ju / (1024.f * ms) + jt / (8.f * ms) + 0.01f * or_sum[0];
  }
}

extern "C" void kernel_launch(void* const* d_in, const int* in_sizes, int n_in,
                              void* d_out, int out_size, void* d_ws, size_t ws_size,
                              hipStream_t stream) {
  const float* v = (const float*)d_in[0];
  const float* vhat = (const float*)d_in[1];
  const float* g = (const float*)d_in[2];
  const float* F = (const float*)d_in[3];
  const float* negs = (const float*)d_in[4];
  const int* mask = (const int*)d_in[5];
  float* out = (float*)d_out;

  char* ws = (char*)d_ws;
  float* true_d = (float*)(ws + 0);                 // 4096 f32
  float* nv2 = (float*)(ws + 16384);                // 4096 f32
  float* colBn = (float*)(ws + 32768);              // 1088 f32
  float* jt_part = (float*)(ws + 37120);            // 1024 f32
  float* ms_part = (float*)(ws + 41216);            // 1024 f32
  float* gemm_part = (float*)(ws + 45312);          // 544 f32
  float* or_sum = (float*)(ws + 47616);             // 1 f32
  float* S = (float*)(ws + 49152);                  // 4096*64 f32 = 1 MB
  unsigned short* A_bf = (unsigned short*)(ws + 1097728);  // 4224x768 bf16 = 6.49 MB
  unsigned short* B_bf = (unsigned short*)(ws + 7585792);  // 1088x768 bf16 = 1.67 MB

  hipLaunchKernelGGL(k_prep, dim3(1312), dim3(256), 0, stream, v, vhat, negs, F,
                     A_bf, B_bf, nv2, true_d, colBn);
  hipLaunchKernelGGL(k_gemm, dim3(545), dim3(256), 0, stream, A_bf, B_bf,
                     nv2, colBn, true_d, mask, S, gemm_part, or_sum);
  hipLaunchKernelGGL(k_jt, dim3(1024), dim3(256), 0, stream, g, S, nv2, true_d,
                     colBn, mask, jt_part, ms_part);
  hipLaunchKernelGGL(k_final, dim3(1), dim3(256), 0, stream, jt_part, ms_part,
                     gemm_part, or_sum, out);
}